// Round 22
// baseline (103.534 us; speedup 1.0000x reference)
//
#include <hip/hip_runtime.h>
#include <hip/hip_bf16.h>
#include <math.h>

#define N_ROWS  100000
#define NT_ROW  6250            // 16-row MFMA tiles, exact

typedef __attribute__((ext_vector_type(8))) short bf16x8;   // 4 VGPR A/B frag
typedef __attribute__((ext_vector_type(4))) float f32x4;    // C/D frag

__device__ __forceinline__ float silu_f(float v) {
    return v * (1.0f / (1.0f + __expf(-v)));
}
__device__ __forceinline__ short f2bf(float f) {
    union { __hip_bfloat16 h; short s; } u;
    u.h = __float2bfloat16(f);          // RNE convert
    return u.s;
}
// async global->LDS with NON-TEMPORAL policy (aux=2): x is a zero-reuse
// stream; no-allocate keeps L2 for the B weights (r17-verified win).
__device__ __forceinline__ void stage16nt(const float* g, float* l) {
    __builtin_amdgcn_global_load_lds(
        (const __attribute__((address_space(1))) unsigned int*)g,
        (__attribute__((address_space(3))) unsigned int*)l,
        16, 0, 2);
}

// ---- pre-kernel: fragment-packed weights (unchanged, verified) -------------
// wTf[(t*8+p)*1024 B + lane*16 B] = B-fragment for col-tile t, K-pass p.
// Main kernel reads tiles 0..11 only (12..19 duplicate 8..11).
__global__ __launch_bounds__(64)
void prep_wT(const float* __restrict__ w1_s, const float* __restrict__ w1_v,
             unsigned short* __restrict__ wTf)
{
    const int tp = blockIdx.x;               // 0..159 = t*8 + p
    const int t = tp >> 3, p = tp & 7;
    const int lane = threadIdx.x;            // 0..63
    const int l15 = lane & 15, lq = lane >> 4;
    const float* src  = (t < 8) ? w1_s : w1_v;
    const int    strd = (t < 8) ? 128 : 64;
    const int    scol = (t < 8) ? (t * 16 + l15) : (((t - 8) & 3) * 16 + l15);
    const int    k0   = 32 * p + 8 * lq;
    unsigned short o[8];
    #pragma unroll
    for (int e = 0; e < 8; ++e)
        o[e] = (unsigned short)f2bf(src[(k0 + e) * strd + scol]);
    *(ushort4*)(wTf + (size_t)tp * 512 + lane * 8)     = make_ushort4(o[0], o[1], o[2], o[3]);
    *(ushort4*)(wTf + (size_t)tp * 512 + lane * 8 + 4) = make_ushort4(o[4], o[5], o[6], o[7]);
}

// ---- main kernel: r21 champion + B register prefetch (1 pass ahead) --------
// Pass p consumes Bcur (loaded during pass p-1 -> full-pass L2-latency cover);
// pass p issues Bnxt = B(p+1) BEFORE stages(p+2), so at each pass top
// vmcnt(8) retires [B(p), stages(p)] and keeps exactly stages(p+1) in flight.
__global__ __launch_bounds__(256, 2)
void ndr_mfma_kernel(const float* __restrict__ x,
                     const unsigned short* __restrict__ wTf,
                     const float* __restrict__ w2_s,
                     const float* __restrict__ w2_v,
                     float* __restrict__ out)
{
    __shared__ float lds[2][4][2048];        // [buf][wave][16*128 floats] = 64 KB

    const int lane = threadIdx.x & 63;
    const int wid  = threadIdx.x >> 6;
    const int rt   = blockIdx.x * 4 + wid;
    if (rt >= NT_ROW) return;                // no barriers anywhere -> safe
    const int l15 = lane & 15, lq = lane >> 4;
    const long long n0 = (long long)rt * 16;

    // --- staging map (constant across passes) ---
    const int sub = lane >> 5, slot = lane & 31;
    const float* sp[8];
    int sstep[8];
    #pragma unroll
    for (int j = 0; j < 8; ++j) {
        const int row = 2 * j + sub;
        const int g   = slot ^ (row & 7);    // inverse-swizzled source segment
        const int isxs = (g < 8);
        const int f0  = isxs ? 4 * g : 256 + 4 * (g - 8);
        sstep[j] = isxs ? 32 : 96;
        sp[j] = x + (n0 + row) * 1024 + f0;
    }

    f32x4 acc[20];
    #pragma unroll
    for (int t = 0; t < 20; ++t) acc[t] = (f32x4){0.f, 0.f, 0.f, 0.f};

    const char* wbase = (const char*)wTf + lane * 16;

    // --- prologue: B(0) FIRST (so vmcnt(8) at pass-0 top retires it), then
    // stage pass 0 -> buf0, pass 1 -> buf1 ---
    bf16x8 bAs[8], bAv[4], bBs[8], bBv[4];
    #pragma unroll
    for (int t = 0; t < 8; ++t)
        bAs[t] = *(const bf16x8*)(wbase + (size_t)t * 8192);
    #pragma unroll
    for (int u = 0; u < 4; ++u)
        bAv[u] = *(const bf16x8*)(wbase + (size_t)(8 + u) * 8192);
    #pragma unroll
    for (int j = 0; j < 8; ++j) stage16nt(sp[j],            &lds[0][wid][j * 256]);
    #pragma unroll
    for (int j = 0; j < 8; ++j) stage16nt(sp[j] + sstep[j], &lds[1][wid][j * 256]);

    const int r7 = l15 & 7;
    const float* rb0 = &lds[0][wid][l15 * 128];
    const float* rb1 = &lds[1][wid][l15 * 128];

    // One K-pass. CURS/CURV: B(p) regs (landed). NXTS/NXTV: B(p+1) dest regs.
    #define PASS(p_, CURS, CURV, NXTS, NXTV)                                   \
    do {                                                                       \
        const int p = (p_);                                                    \
        if (p < 7) asm volatile("s_waitcnt vmcnt(8)" ::: "memory");            \
        else       asm volatile("s_waitcnt vmcnt(0)" ::: "memory");            \
        const float* rb = (p & 1) ? rb1 : rb0;                                 \
        f32x4 s0 = *(const f32x4*)(rb + 4 * (( 2 * lq     ) ^ r7));            \
        f32x4 s1 = *(const f32x4*)(rb + 4 * (( 2 * lq + 1 ) ^ r7));            \
        f32x4 v0 = *(const f32x4*)(rb + 4 * ((8 + 6 * lq + 0) ^ r7));          \
        f32x4 v1 = *(const f32x4*)(rb + 4 * ((8 + 6 * lq + 1) ^ r7));          \
        f32x4 v2 = *(const f32x4*)(rb + 4 * ((8 + 6 * lq + 2) ^ r7));          \
        f32x4 v3 = *(const f32x4*)(rb + 4 * ((8 + 6 * lq + 3) ^ r7));          \
        f32x4 v4 = *(const f32x4*)(rb + 4 * ((8 + 6 * lq + 4) ^ r7));          \
        f32x4 v5 = *(const f32x4*)(rb + 4 * ((8 + 6 * lq + 5) ^ r7));          \
        /* issue B(p+1) -> NXT regs (consumed next pass; no wait here) */      \
        if (p + 1 < 8) {                                                       \
            _Pragma("unroll")                                                  \
            for (int t = 0; t < 8; ++t)                                        \
                NXTS[t] = *(const bf16x8*)(wbase + (size_t)(p + 1) * 1024      \
                                                 + (size_t)t * 8192);          \
            _Pragma("unroll")                                                  \
            for (int u = 0; u < 4; ++u)                                        \
                NXTV[u] = *(const bf16x8*)(wbase + (size_t)(p + 1) * 1024      \
                                                 + (size_t)(8 + u) * 8192);    \
        }                                                                      \
        /* LDS reads done -> safe to overwrite buf with stages(p+2) */         \
        if (p + 2 < 8) {                                                       \
            asm volatile("s_waitcnt lgkmcnt(0)" ::: "memory");                 \
            _Pragma("unroll")                                                  \
            for (int j = 0; j < 8; ++j)                                        \
                stage16nt(sp[j] + (p + 2) * sstep[j], &lds[p & 1][wid][j * 256]); \
        }                                                                      \
        const float xs[8]  = {s0.x, s0.y, s0.z, s0.w, s1.x, s1.y, s1.z, s1.w}; \
        const float xv[24] = {v0.x, v0.y, v0.z, v0.w, v1.x, v1.y, v1.z, v1.w,  \
                              v2.x, v2.y, v2.z, v2.w, v3.x, v3.y, v3.z, v3.w,  \
                              v4.x, v4.y, v4.z, v4.w, v5.x, v5.y, v5.z, v5.w}; \
        bf16x8 a_s, a_v0, a_v1, a_v2;                                          \
        _Pragma("unroll")                                                      \
        for (int e = 0; e < 8; ++e) {                                          \
            a_s[e]  = f2bf(xs[e]);                                             \
            a_v0[e] = f2bf(xv[3 * e + 0]);                                     \
            a_v1[e] = f2bf(xv[3 * e + 1]);                                     \
            a_v2[e] = f2bf(xv[3 * e + 2]);                                     \
        }                                                                      \
        _Pragma("unroll")                                                      \
        for (int t = 0; t < 8; ++t)                                            \
            acc[t] = __builtin_amdgcn_mfma_f32_16x16x32_bf16(a_s, CURS[t],     \
                                                             acc[t], 0, 0, 0); \
        _Pragma("unroll")                                                      \
        for (int u = 0; u < 4; ++u) {                                          \
            acc[8  + u] = __builtin_amdgcn_mfma_f32_16x16x32_bf16(a_v0, CURV[u], acc[8  + u], 0, 0, 0); \
            acc[12 + u] = __builtin_amdgcn_mfma_f32_16x16x32_bf16(a_v1, CURV[u], acc[12 + u], 0, 0, 0); \
            acc[16 + u] = __builtin_amdgcn_mfma_f32_16x16x32_bf16(a_v2, CURV[u], acc[16 + u], 0, 0, 0); \
        }                                                                      \
    } while (0)

    #pragma unroll 1
    for (int pp = 0; pp < 4; ++pp) {         // unroll x2: static B ping-pong
        PASS(2 * pp,     bAs, bAv, bBs, bBv);
        PASS(2 * pp + 1, bBs, bBv, bAs, bAv);
    }
    #undef PASS

    // ---- epilogue: silu-gate + layer 2 in fp32 (unchanged, verified) -------
    const float inv_in = 0.0625f, inv_h = 0.125f;
    float w2sv[4], w2vv[4];
    #pragma unroll
    for (int u = 0; u < 4; ++u) {
        w2sv[u] = w2_s[u * 16 + l15];
        w2vv[u] = w2_v[u * 16 + l15];
    }
    #pragma unroll
    for (int j = 0; j < 4; ++j) {
        float ps = 0.f, pv0 = 0.f, pv1 = 0.f, pv2 = 0.f;
        #pragma unroll
        for (int u = 0; u < 4; ++u) {
            float hs = acc[u][j]     * inv_in;
            float hg = acc[4 + u][j] * inv_in;
            float gg = silu_f(hg);
            ps  += silu_f(hs) * w2sv[u];
            pv0 += gg * (acc[8  + u][j] * inv_in) * w2vv[u];
            pv1 += gg * (acc[12 + u][j] * inv_in) * w2vv[u];
            pv2 += gg * (acc[16 + u][j] * inv_in) * w2vv[u];
        }
        #pragma unroll
        for (int off = 1; off <= 8; off <<= 1) {
            ps  += __shfl_xor(ps,  off, 64);
            pv0 += __shfl_xor(pv0, off, 64);
            pv1 += __shfl_xor(pv1, off, 64);
            pv2 += __shfl_xor(pv2, off, 64);
        }
        if (l15 == 0) {
            long long n = n0 + lq * 4 + j;
            *(float4*)(out + n * 4) =
                make_float4(ps * inv_h, pv0 * inv_h, pv1 * inv_h, pv2 * inv_h);
        }
    }
}

extern "C" void kernel_launch(void* const* d_in, const int* in_sizes, int n_in,
                              void* d_out, int out_size, void* d_ws, size_t ws_size,
                              hipStream_t stream) {
    const float* x    = (const float*)d_in[0];
    const float* w1_s = (const float*)d_in[1];
    const float* w1_v = (const float*)d_in[2];
    const float* w2_s = (const float*)d_in[3];
    const float* w2_v = (const float*)d_in[4];
    float* out = (float*)d_out;
    unsigned short* wTf = (unsigned short*)d_ws;      // 160*512*2 = 160 KB

    prep_wT<<<160, 64, 0, stream>>>(w1_s, w1_v, wTf);
    int blocks = (NT_ROW + 3) / 4;                    // 1563; tail waves exit
    ndr_mfma_kernel<<<blocks, 256, 0, stream>>>(x, wTf, w2_s, w2_v, out);
}

// Round 23
// 94.128 us; speedup vs baseline: 1.0999x; 1.0999x over previous
//
#include <hip/hip_runtime.h>
#include <hip/hip_bf16.h>
#include <math.h>

#define N_ROWS  100000
#define NT_ROW  6250            // 16-row MFMA tiles, exact

typedef __attribute__((ext_vector_type(8))) short bf16x8;   // 4 VGPR A/B frag
typedef __attribute__((ext_vector_type(4))) float f32x4;    // C/D frag

__device__ __forceinline__ float silu_f(float v) {
    return v * (1.0f / (1.0f + __expf(-v)));
}
__device__ __forceinline__ short f2bf(float f) {
    union { __hip_bfloat16 h; short s; } u;
    u.h = __float2bfloat16(f);          // RNE convert
    return u.s;
}
// async global->LDS with NON-TEMPORAL policy (aux=2): x is a zero-reuse
// stream; no-allocate keeps L2 for the B weights (r17-verified win).
__device__ __forceinline__ void stage16nt(const float* g, float* l) {
    __builtin_amdgcn_global_load_lds(
        (const __attribute__((address_space(1))) unsigned int*)g,
        (__attribute__((address_space(3))) unsigned int*)l,
        16, 0, 2);
}

// ---- pre-kernel: fragment-packed weights (unchanged, verified) -------------
// wTf[(t*8+p)*1024 B + lane*16 B] = B-fragment for col-tile t, K-pass p.
// Main kernel reads tiles 0..11 only (12..19 duplicate 8..11).
__global__ __launch_bounds__(64)
void prep_wT(const float* __restrict__ w1_s, const float* __restrict__ w1_v,
             unsigned short* __restrict__ wTf)
{
    const int tp = blockIdx.x;               // 0..159 = t*8 + p
    const int t = tp >> 3, p = tp & 7;
    const int lane = threadIdx.x;            // 0..63
    const int l15 = lane & 15, lq = lane >> 4;
    const float* src  = (t < 8) ? w1_s : w1_v;
    const int    strd = (t < 8) ? 128 : 64;
    const int    scol = (t < 8) ? (t * 16 + l15) : (((t - 8) & 3) * 16 + l15);
    const int    k0   = 32 * p + 8 * lq;
    unsigned short o[8];
    #pragma unroll
    for (int e = 0; e < 8; ++e)
        o[e] = (unsigned short)f2bf(src[(k0 + e) * strd + scol]);
    *(ushort4*)(wTf + (size_t)tp * 512 + lane * 8)     = make_ushort4(o[0], o[1], o[2], o[3]);
    *(ushort4*)(wTf + (size_t)tp * 512 + lane * 8 + 4) = make_ushort4(o[4], o[5], o[6], o[7]);
}

// ---- main kernel: r21 champion + EARLY B issue (zero-register reorder) -----
// B loads move to right after the pass-top vmcnt wait: the ds_read latency
// (~120cy) + 32 cvts (~150cy) now cover B's L1/L2 latency before the MFMAs.
// vmcnt bookkeeping unchanged: B(p) is older than stages(p+2), so the
// compiler's pre-MFMA wait stays vmcnt(8). No extra VGPRs (r22 lesson).
__global__ __launch_bounds__(256, 2)
void ndr_mfma_kernel(const float* __restrict__ x,
                     const unsigned short* __restrict__ wTf,
                     const float* __restrict__ w2_s,
                     const float* __restrict__ w2_v,
                     float* __restrict__ out)
{
    __shared__ float lds[2][4][2048];        // [buf][wave][16*128 floats] = 64 KB

    const int lane = threadIdx.x & 63;
    const int wid  = threadIdx.x >> 6;
    const int rt   = blockIdx.x * 4 + wid;
    if (rt >= NT_ROW) return;                // no barriers anywhere -> safe
    const int l15 = lane & 15, lq = lane >> 4;
    const long long n0 = (long long)rt * 16;

    // --- staging map (constant across passes) ---
    const int sub = lane >> 5, slot = lane & 31;
    const float* sp[8];
    int sstep[8];
    #pragma unroll
    for (int j = 0; j < 8; ++j) {
        const int row = 2 * j + sub;
        const int g   = slot ^ (row & 7);    // inverse-swizzled source segment
        const int isxs = (g < 8);
        const int f0  = isxs ? 4 * g : 256 + 4 * (g - 8);
        sstep[j] = isxs ? 32 : 96;
        sp[j] = x + (n0 + row) * 1024 + f0;
    }

    f32x4 acc[20];
    #pragma unroll
    for (int t = 0; t < 20; ++t) acc[t] = (f32x4){0.f, 0.f, 0.f, 0.f};

    const char* wbase = (const char*)wTf + lane * 16;

    // --- prologue: stage pass 0 -> buf0, pass 1 -> buf1 ---
    #pragma unroll
    for (int j = 0; j < 8; ++j) stage16nt(sp[j],            &lds[0][wid][j * 256]);
    #pragma unroll
    for (int j = 0; j < 8; ++j) stage16nt(sp[j] + sstep[j], &lds[1][wid][j * 256]);

    const int r7 = l15 & 7;
    const float* rb0 = &lds[0][wid][l15 * 128];
    const float* rb1 = &lds[1][wid][l15 * 128];

    #pragma unroll 1
    for (int p = 0; p < 8; ++p) {
        // buf[p&1] ready when everything older than the newest 8 stages landed
        if (p < 7) asm volatile("s_waitcnt vmcnt(8)" ::: "memory");
        else       asm volatile("s_waitcnt vmcnt(0)" ::: "memory");

        // EARLY B issue (dedup: 8 s-fragments + 4 distinct v-fragments);
        // latency hides under the ds_read+cvt block below.
        bf16x8 bfs[8], bfv[4];
        #pragma unroll
        for (int t = 0; t < 8; ++t)
            bfs[t] = *(const bf16x8*)(wbase + (size_t)p * 1024 + (size_t)t * 8192);
        #pragma unroll
        for (int u = 0; u < 4; ++u)
            bfv[u] = *(const bf16x8*)(wbase + (size_t)p * 1024 + (size_t)(8 + u) * 8192);

        const float* rb = (p & 1) ? rb1 : rb0;
        // xs: segs 2lq, 2lq+1 ; xv: segs 8+6lq..8+6lq+5 (slot = seg ^ r7)
        f32x4 s0 = *(const f32x4*)(rb + 4 * (( 2 * lq     ) ^ r7));
        f32x4 s1 = *(const f32x4*)(rb + 4 * (( 2 * lq + 1 ) ^ r7));
        f32x4 v0 = *(const f32x4*)(rb + 4 * ((8 + 6 * lq + 0) ^ r7));
        f32x4 v1 = *(const f32x4*)(rb + 4 * ((8 + 6 * lq + 1) ^ r7));
        f32x4 v2 = *(const f32x4*)(rb + 4 * ((8 + 6 * lq + 2) ^ r7));
        f32x4 v3 = *(const f32x4*)(rb + 4 * ((8 + 6 * lq + 3) ^ r7));
        f32x4 v4 = *(const f32x4*)(rb + 4 * ((8 + 6 * lq + 4) ^ r7));
        f32x4 v5 = *(const f32x4*)(rb + 4 * ((8 + 6 * lq + 5) ^ r7));

        const float xs[8]  = {s0.x, s0.y, s0.z, s0.w, s1.x, s1.y, s1.z, s1.w};
        const float xv[24] = {v0.x, v0.y, v0.z, v0.w, v1.x, v1.y, v1.z, v1.w,
                              v2.x, v2.y, v2.z, v2.w, v3.x, v3.y, v3.z, v3.w,
                              v4.x, v4.y, v4.z, v4.w, v5.x, v5.y, v5.z, v5.w};
        bf16x8 a_s, a_v0, a_v1, a_v2;        // A[row=l15][k=32p+8lq+e]
        #pragma unroll
        for (int e = 0; e < 8; ++e) {
            a_s[e]  = f2bf(xs[e]);
            a_v0[e] = f2bf(xv[3 * e + 0]);
            a_v1[e] = f2bf(xv[3 * e + 1]);
            a_v2[e] = f2bf(xv[3 * e + 2]);
        }

        // overwrite the just-consumed buffer with pass p+2 (LDS reads fenced)
        if (p + 2 < 8) {
            asm volatile("s_waitcnt lgkmcnt(0)" ::: "memory");
            #pragma unroll
            for (int j = 0; j < 8; ++j)
                stage16nt(sp[j] + (p + 2) * sstep[j], &lds[p & 1][wid][j * 256]);
        }

        #pragma unroll
        for (int t = 0; t < 8; ++t)
            acc[t] = __builtin_amdgcn_mfma_f32_16x16x32_bf16(a_s, bfs[t], acc[t], 0, 0, 0);
        #pragma unroll
        for (int u = 0; u < 4; ++u) {
            acc[8  + u] = __builtin_amdgcn_mfma_f32_16x16x32_bf16(a_v0, bfv[u], acc[8  + u], 0, 0, 0);
            acc[12 + u] = __builtin_amdgcn_mfma_f32_16x16x32_bf16(a_v1, bfv[u], acc[12 + u], 0, 0, 0);
            acc[16 + u] = __builtin_amdgcn_mfma_f32_16x16x32_bf16(a_v2, bfv[u], acc[16 + u], 0, 0, 0);
        }
    }

    // ---- epilogue: silu-gate + layer 2 in fp32 (unchanged, verified) -------
    const float inv_in = 0.0625f, inv_h = 0.125f;
    float w2sv[4], w2vv[4];
    #pragma unroll
    for (int u = 0; u < 4; ++u) {
        w2sv[u] = w2_s[u * 16 + l15];
        w2vv[u] = w2_v[u * 16 + l15];
    }
    #pragma unroll
    for (int j = 0; j < 4; ++j) {
        float ps = 0.f, pv0 = 0.f, pv1 = 0.f, pv2 = 0.f;
        #pragma unroll
        for (int u = 0; u < 4; ++u) {
            float hs = acc[u][j]     * inv_in;
            float hg = acc[4 + u][j] * inv_in;
            float gg = silu_f(hg);
            ps  += silu_f(hs) * w2sv[u];
            pv0 += gg * (acc[8  + u][j] * inv_in) * w2vv[u];
            pv1 += gg * (acc[12 + u][j] * inv_in) * w2vv[u];
            pv2 += gg * (acc[16 + u][j] * inv_in) * w2vv[u];
        }
        #pragma unroll
        for (int off = 1; off <= 8; off <<= 1) {
            ps  += __shfl_xor(ps,  off, 64);
            pv0 += __shfl_xor(pv0, off, 64);
            pv1 += __shfl_xor(pv1, off, 64);
            pv2 += __shfl_xor(pv2, off, 64);
        }
        if (l15 == 0) {
            long long n = n0 + lq * 4 + j;
            *(float4*)(out + n * 4) =
                make_float4(ps * inv_h, pv0 * inv_h, pv1 * inv_h, pv2 * inv_h);
        }
    }
}

extern "C" void kernel_launch(void* const* d_in, const int* in_sizes, int n_in,
                              void* d_out, int out_size, void* d_ws, size_t ws_size,
                              hipStream_t stream) {
    const float* x    = (const float*)d_in[0];
    const float* w1_s = (const float*)d_in[1];
    const float* w1_v = (const float*)d_in[2];
    const float* w2_s = (const float*)d_in[3];
    const float* w2_v = (const float*)d_in[4];
    float* out = (float*)d_out;
    unsigned short* wTf = (unsigned short*)d_ws;      // 160*512*2 = 160 KB

    prep_wT<<<160, 64, 0, stream>>>(w1_s, w1_v, wTf);
    int blocks = (NT_ROW + 3) / 4;                    // 1563; tail waves exit
    ndr_mfma_kernel<<<blocks, 256, 0, stream>>>(x, wTf, w2_s, w2_v, out);
}

// Round 24
// 94.043 us; speedup vs baseline: 1.1009x; 1.0009x over previous
//
#include <hip/hip_runtime.h>
#include <hip/hip_bf16.h>
#include <math.h>

#define N_ROWS  100000
#define NT_ROW  6250            // 16-row MFMA tiles, exact

typedef __attribute__((ext_vector_type(8))) short bf16x8;   // 4 VGPR A/B frag
typedef __attribute__((ext_vector_type(4))) float f32x4;    // C/D frag

__device__ __forceinline__ float silu_f(float v) {
    return v * (1.0f / (1.0f + __expf(-v)));
}
__device__ __forceinline__ short f2bf(float f) {
    union { __hip_bfloat16 h; short s; } u;
    u.h = __float2bfloat16(f);          // RNE convert
    return u.s;
}
// async global->LDS, non-temporal at BOTH cache levels (aux = NT|SC1 = 0x12):
// x is a zero-reuse stream; r17 proved NT(L2) = +7.4us; this A/Bs the L3 bit.
__device__ __forceinline__ void stage16nt(const float* g, float* l) {
    __builtin_amdgcn_global_load_lds(
        (const __attribute__((address_space(1))) unsigned int*)g,
        (__attribute__((address_space(3))) unsigned int*)l,
        16, 0, 18);
}

// ---- pre-kernel: fragment-packed weights (unchanged, verified) -------------
// wTf[(t*8+p)*1024 B + lane*16 B] = B-fragment for col-tile t, K-pass p.
// Main kernel reads tiles 0..11 only (12..19 duplicate 8..11).
__global__ __launch_bounds__(64)
void prep_wT(const float* __restrict__ w1_s, const float* __restrict__ w1_v,
             unsigned short* __restrict__ wTf)
{
    const int tp = blockIdx.x;               // 0..159 = t*8 + p
    const int t = tp >> 3, p = tp & 7;
    const int lane = threadIdx.x;            // 0..63
    const int l15 = lane & 15, lq = lane >> 4;
    const float* src  = (t < 8) ? w1_s : w1_v;
    const int    strd = (t < 8) ? 128 : 64;
    const int    scol = (t < 8) ? (t * 16 + l15) : (((t - 8) & 3) * 16 + l15);
    const int    k0   = 32 * p + 8 * lq;
    unsigned short o[8];
    #pragma unroll
    for (int e = 0; e < 8; ++e)
        o[e] = (unsigned short)f2bf(src[(k0 + e) * strd + scol]);
    *(ushort4*)(wTf + (size_t)tp * 512 + lane * 8)     = make_ushort4(o[0], o[1], o[2], o[3]);
    *(ushort4*)(wTf + (size_t)tp * 512 + lane * 8 + 4) = make_ushort4(o[4], o[5], o[6], o[7]);
}

// ---- main kernel: r21/r23 champion, x stages NT at L2 AND L3 ---------------
__global__ __launch_bounds__(256, 2)
void ndr_mfma_kernel(const float* __restrict__ x,
                     const unsigned short* __restrict__ wTf,
                     const float* __restrict__ w2_s,
                     const float* __restrict__ w2_v,
                     float* __restrict__ out)
{
    __shared__ float lds[2][4][2048];        // [buf][wave][16*128 floats] = 64 KB

    const int lane = threadIdx.x & 63;
    const int wid  = threadIdx.x >> 6;
    const int rt   = blockIdx.x * 4 + wid;
    if (rt >= NT_ROW) return;                // no barriers anywhere -> safe
    const int l15 = lane & 15, lq = lane >> 4;
    const long long n0 = (long long)rt * 16;

    // --- staging map (constant across passes) ---
    const int sub = lane >> 5, slot = lane & 31;
    const float* sp[8];
    int sstep[8];
    #pragma unroll
    for (int j = 0; j < 8; ++j) {
        const int row = 2 * j + sub;
        const int g   = slot ^ (row & 7);    // inverse-swizzled source segment
        const int isxs = (g < 8);
        const int f0  = isxs ? 4 * g : 256 + 4 * (g - 8);
        sstep[j] = isxs ? 32 : 96;
        sp[j] = x + (n0 + row) * 1024 + f0;
    }

    f32x4 acc[20];
    #pragma unroll
    for (int t = 0; t < 20; ++t) acc[t] = (f32x4){0.f, 0.f, 0.f, 0.f};

    const char* wbase = (const char*)wTf + lane * 16;

    // --- prologue: stage pass 0 -> buf0, pass 1 -> buf1 ---
    #pragma unroll
    for (int j = 0; j < 8; ++j) stage16nt(sp[j],            &lds[0][wid][j * 256]);
    #pragma unroll
    for (int j = 0; j < 8; ++j) stage16nt(sp[j] + sstep[j], &lds[1][wid][j * 256]);

    const int r7 = l15 & 7;
    const float* rb0 = &lds[0][wid][l15 * 128];
    const float* rb1 = &lds[1][wid][l15 * 128];

    #pragma unroll 1
    for (int p = 0; p < 8; ++p) {
        // buf[p&1] ready when everything older than the newest 8 stages landed
        if (p < 7) asm volatile("s_waitcnt vmcnt(8)" ::: "memory");
        else       asm volatile("s_waitcnt vmcnt(0)" ::: "memory");

        // B issue (dedup: 8 s-fragments + 4 distinct v-fragments)
        bf16x8 bfs[8], bfv[4];
        #pragma unroll
        for (int t = 0; t < 8; ++t)
            bfs[t] = *(const bf16x8*)(wbase + (size_t)p * 1024 + (size_t)t * 8192);
        #pragma unroll
        for (int u = 0; u < 4; ++u)
            bfv[u] = *(const bf16x8*)(wbase + (size_t)p * 1024 + (size_t)(8 + u) * 8192);

        const float* rb = (p & 1) ? rb1 : rb0;
        // xs: segs 2lq, 2lq+1 ; xv: segs 8+6lq..8+6lq+5 (slot = seg ^ r7)
        f32x4 s0 = *(const f32x4*)(rb + 4 * (( 2 * lq     ) ^ r7));
        f32x4 s1 = *(const f32x4*)(rb + 4 * (( 2 * lq + 1 ) ^ r7));
        f32x4 v0 = *(const f32x4*)(rb + 4 * ((8 + 6 * lq + 0) ^ r7));
        f32x4 v1 = *(const f32x4*)(rb + 4 * ((8 + 6 * lq + 1) ^ r7));
        f32x4 v2 = *(const f32x4*)(rb + 4 * ((8 + 6 * lq + 2) ^ r7));
        f32x4 v3 = *(const f32x4*)(rb + 4 * ((8 + 6 * lq + 3) ^ r7));
        f32x4 v4 = *(const f32x4*)(rb + 4 * ((8 + 6 * lq + 4) ^ r7));
        f32x4 v5 = *(const f32x4*)(rb + 4 * ((8 + 6 * lq + 5) ^ r7));

        const float xs[8]  = {s0.x, s0.y, s0.z, s0.w, s1.x, s1.y, s1.z, s1.w};
        const float xv[24] = {v0.x, v0.y, v0.z, v0.w, v1.x, v1.y, v1.z, v1.w,
                              v2.x, v2.y, v2.z, v2.w, v3.x, v3.y, v3.z, v3.w,
                              v4.x, v4.y, v4.z, v4.w, v5.x, v5.y, v5.z, v5.w};
        bf16x8 a_s, a_v0, a_v1, a_v2;        // A[row=l15][k=32p+8lq+e]
        #pragma unroll
        for (int e = 0; e < 8; ++e) {
            a_s[e]  = f2bf(xs[e]);
            a_v0[e] = f2bf(xv[3 * e + 0]);
            a_v1[e] = f2bf(xv[3 * e + 1]);
            a_v2[e] = f2bf(xv[3 * e + 2]);
        }

        // overwrite the just-consumed buffer with pass p+2 (LDS reads fenced)
        if (p + 2 < 8) {
            asm volatile("s_waitcnt lgkmcnt(0)" ::: "memory");
            #pragma unroll
            for (int j = 0; j < 8; ++j)
                stage16nt(sp[j] + (p + 2) * sstep[j], &lds[p & 1][wid][j * 256]);
        }

        #pragma unroll
        for (int t = 0; t < 8; ++t)
            acc[t] = __builtin_amdgcn_mfma_f32_16x16x32_bf16(a_s, bfs[t], acc[t], 0, 0, 0);
        #pragma unroll
        for (int u = 0; u < 4; ++u) {
            acc[8  + u] = __builtin_amdgcn_mfma_f32_16x16x32_bf16(a_v0, bfv[u], acc[8  + u], 0, 0, 0);
            acc[12 + u] = __builtin_amdgcn_mfma_f32_16x16x32_bf16(a_v1, bfv[u], acc[12 + u], 0, 0, 0);
            acc[16 + u] = __builtin_amdgcn_mfma_f32_16x16x32_bf16(a_v2, bfv[u], acc[16 + u], 0, 0, 0);
        }
    }

    // ---- epilogue: silu-gate + layer 2 in fp32 (unchanged, verified) -------
    const float inv_in = 0.0625f, inv_h = 0.125f;
    float w2sv[4], w2vv[4];
    #pragma unroll
    for (int u = 0; u < 4; ++u) {
        w2sv[u] = w2_s[u * 16 + l15];
        w2vv[u] = w2_v[u * 16 + l15];
    }
    #pragma unroll
    for (int j = 0; j < 4; ++j) {
        float ps = 0.f, pv0 = 0.f, pv1 = 0.f, pv2 = 0.f;
        #pragma unroll
        for (int u = 0; u < 4; ++u) {
            float hs = acc[u][j]     * inv_in;
            float hg = acc[4 + u][j] * inv_in;
            float gg = silu_f(hg);
            ps  += silu_f(hs) * w2sv[u];
            pv0 += gg * (acc[8  + u][j] * inv_in) * w2vv[u];
            pv1 += gg * (acc[12 + u][j] * inv_in) * w2vv[u];
            pv2 += gg * (acc[16 + u][j] * inv_in) * w2vv[u];
        }
        #pragma unroll
        for (int off = 1; off <= 8; off <<= 1) {
            ps  += __shfl_xor(ps,  off, 64);
            pv0 += __shfl_xor(pv0, off, 64);
            pv1 += __shfl_xor(pv1, off, 64);
            pv2 += __shfl_xor(pv2, off, 64);
        }
        if (l15 == 0) {
            long long n = n0 + lq * 4 + j;
            *(float4*)(out + n * 4) =
                make_float4(ps * inv_h, pv0 * inv_h, pv1 * inv_h, pv2 * inv_h);
        }
    }
}

extern "C" void kernel_launch(void* const* d_in, const int* in_sizes, int n_in,
                              void* d_out, int out_size, void* d_ws, size_t ws_size,
                              hipStream_t stream) {
    const float* x    = (const float*)d_in[0];
    const float* w1_s = (const float*)d_in[1];
    const float* w1_v = (const float*)d_in[2];
    const float* w2_s = (const float*)d_in[3];
    const float* w2_v = (const float*)d_in[4];
    float* out = (float*)d_out;
    unsigned short* wTf = (unsigned short*)d_ws;      // 160*512*2 = 160 KB

    prep_wT<<<160, 64, 0, stream>>>(w1_s, w1_v, wTf);
    int blocks = (NT_ROW + 3) / 4;                    // 1563; tail waves exit
    ndr_mfma_kernel<<<blocks, 256, 0, stream>>>(x, wTf, w2_s, w2_v, out);
}